// Round 7
// baseline (213.280 us; speedup 1.0000x reference)
//
#include <hip/hip_runtime.h>
#include <hip/hip_bf16.h>

typedef _Float16 half4_t __attribute__((ext_vector_type(4)));
typedef _Float16 half8_t __attribute__((ext_vector_type(8)));
typedef float    float4_t __attribute__((ext_vector_type(4)));

#define MFMA32(a, b, c) __builtin_amdgcn_mfma_f32_16x16x32_f16((a), (b), (c), 0, 0, 0)

constexpr int  Bb  = 1024;
constexpr long CTX = (long)Bb * 64 * 512;      // attn offset in d_out
constexpr int  SQP = 520;                      // shared q/V^T row stride (halves)
constexpr int  QTP = 72;                       // qT row stride (halves), kernel B

// ---- pre-pass: pack W (f32 [e][f]) into fragment layout fp16 ----
// W2[(E*16+c)*512 + lane*8 + j] = W[E*16 + (lane&15)][c*32 + (lane>>4)*8 + j]
__global__ void w_pack(const float* __restrict__ W, _Float16* __restrict__ W2) {
    const int t = blockIdx.x * 256 + threadIdx.x;      // 32768 threads
    const int lane = t & 63, grp = t >> 6;             // grp 0..511
    const int E = grp >> 4, c = grp & 15;
    const int r16 = lane & 15, q = lane >> 4;
    const float* src = W + (long)(E * 16 + r16) * 512 + c * 32 + q * 8;
    float4_t x = *(const float4_t*)(src);
    float4_t y = *(const float4_t*)(src + 4);
    half8_t h;
    h[0]=(_Float16)x[0]; h[1]=(_Float16)x[1]; h[2]=(_Float16)x[2]; h[3]=(_Float16)x[3];
    h[4]=(_Float16)y[0]; h[5]=(_Float16)y[1]; h[6]=(_Float16)y[2]; h[7]=(_Float16)y[3];
    *(half8_t*)(W2 + (long)t * 8) = h;
}

// ---- kernel A: stage q -> LDS; V^T = q*W^T; V^T overwrites q;
//      score = M*V streamed (3-deep reg prefetch); softmax -> attn ----
__global__ __launch_bounds__(512, 2)     // allow up to 256 VGPR; LDS caps at 2 blk/CU anyway
void ovo_score(const float* __restrict__ o1, const float* __restrict__ o2,
               const float* __restrict__ o3, const float* __restrict__ qm,
               const _Float16* __restrict__ W2, float* __restrict__ out)
{
    __shared__ __align__(16) _Float16 sQ[64 * SQP];   // q fp16 [g][f], later V^T [g][e]; 66.6 KB

    const int t = threadIdx.x, lane = t & 63, w = t >> 6;
    const int r16 = lane & 15, q = lane >> 4;
    const long base = (long)blockIdx.x * 64 * 512;
    const float4_t zf4 = {0.f, 0.f, 0.f, 0.f};

    // ---- stage q (fp16) once: 8 threads/row, coalesced dwordx4, independent loads ----
    {
        const int srow = t >> 3;              // 0..63 (g)
        const int sf   = (t & 7) * 4;         // col base
        const float* qsrc = qm + base + (long)srow * 512 + sf;
        _Float16*    qdst = &sQ[srow * SQP + sf];
        #pragma unroll
        for (int k = 0; k < 16; ++k) {
            float4_t v = *(const float4_t*)(qsrc + k * 32);
            half4_t h;
            h[0]=(_Float16)v[0]; h[1]=(_Float16)v[1]; h[2]=(_Float16)v[2]; h[3]=(_Float16)v[3];
            *(half4_t*)(qdst + k * 32) = h;
        }
    }
    __syncthreads();

    // ---- phase V: V^T[g][e] = sum_f q[g,f]*W[e,f]; wave w owns e-slice [64w,64w+64) ----
    float4_t vacc[4][4];   // [gt][et]
    #pragma unroll
    for (int i = 0; i < 4; ++i)
        #pragma unroll
        for (int j = 0; j < 4; ++j) vacc[i][j] = zf4;

    #pragma unroll
    for (int c = 0; c < 16; ++c) {
        half8_t Aq[4], Bw[4];
        #pragma unroll
        for (int gt = 0; gt < 4; ++gt)
            Aq[gt] = *(const half8_t*)(&sQ[(gt * 16 + r16) * SQP + c * 32 + q * 8]);
        #pragma unroll
        for (int et = 0; et < 4; ++et)
            Bw[et] = *(const half8_t*)(W2 + (long)((w * 4 + et) * 16 + c) * 512 + lane * 8);
        #pragma unroll
        for (int gt = 0; gt < 4; ++gt)
            #pragma unroll
            for (int et = 0; et < 4; ++et)
                vacc[gt][et] = MFMA32(Aq[gt], Bw[et], vacc[gt][et]);
    }

    // ---- q dead: overwrite sQ with V^T [g][e] ----
    __syncthreads();
    #pragma unroll
    for (int gt = 0; gt < 4; ++gt)
        #pragma unroll
        for (int et = 0; et < 4; ++et)
            #pragma unroll
            for (int r = 0; r < 4; ++r)
                sQ[(gt * 16 + q * 4 + r) * SQP + w * 64 + et * 16 + r16] =
                    (_Float16)vacc[gt][et][r];
    __syncthreads();

    // ---- phase S: score = M * V, 3-deep register prefetch, no barriers ----
    const int ht = w & 3, eh = w >> 2;           // h-tile, e-half
    const long abase = base + (long)(ht * 16 + r16) * 512 + eh * 256 + q * 8;
    const int esV = eh * 256 + q * 8;

    float4_t sacc[4];
    #pragma unroll
    for (int i = 0; i < 4; ++i) sacc[i] = zf4;

    float4_t a1A, b1A, a2A, b2A, a3A, b3A;       // set A
    float4_t a1B, b1B, a2B, b2B, a3B, b3B;       // set B
    float4_t a1C, b1C, a2C, b2C, a3C, b3C;       // set C

    #define SLOAD(S, c) do { \
        const long o_ = abase + (c) * 32; \
        a1##S = *(const float4_t*)(o1 + o_); b1##S = *(const float4_t*)(o1 + o_ + 4); \
        a2##S = *(const float4_t*)(o2 + o_); b2##S = *(const float4_t*)(o2 + o_ + 4); \
        a3##S = *(const float4_t*)(o3 + o_); b3##S = *(const float4_t*)(o3 + o_ + 4); \
    } while (0)

    #define SCOMP(S, c) do { \
        float4_t m0 = (a1##S + a2##S + a3##S) * (1.0f / 3.0f); \
        float4_t m1 = (b1##S + b2##S + b3##S) * (1.0f / 3.0f); \
        half8_t af; \
        af[0]=(_Float16)m0[0]; af[1]=(_Float16)m0[1]; af[2]=(_Float16)m0[2]; af[3]=(_Float16)m0[3]; \
        af[4]=(_Float16)m1[0]; af[5]=(_Float16)m1[1]; af[6]=(_Float16)m1[2]; af[7]=(_Float16)m1[3]; \
        _Pragma("unroll") \
        for (int gt = 0; gt < 4; ++gt) { \
            half8_t bf = *(const half8_t*)(&sQ[(gt * 16 + r16) * SQP + esV + (c) * 32]); \
            sacc[gt] = MFMA32(af, bf, sacc[gt]); \
        } \
    } while (0)

    SLOAD(A, 0); SLOAD(B, 1); SLOAD(C, 2);
    SCOMP(A, 0); SLOAD(A, 3);
    SCOMP(B, 1); SLOAD(B, 4);
    SCOMP(C, 2); SLOAD(C, 5);
    SCOMP(A, 3); SLOAD(A, 6);
    SCOMP(B, 4); SLOAD(B, 7);
    SCOMP(C, 5);
    SCOMP(A, 6);
    SCOMP(B, 7);

    // ---- reduce e-halves + softmax (in regs) ----
    __syncthreads();                              // all sQ (V^T) reads done
    float* part = reinterpret_cast<float*>(sQ);   // 16 KB overlay
    if (w >= 4) {
        #pragma unroll
        for (int gt = 0; gt < 4; ++gt)
            *(float4_t*)(&part[(((w - 4) * 4 + gt) * 64 + lane) * 4]) = sacc[gt];
    }
    __syncthreads();
    if (w < 4) {
        #pragma unroll
        for (int gt = 0; gt < 4; ++gt)
            sacc[gt] += *(const float4_t*)(&part[((w * 4 + gt) * 64 + lane) * 4]);
        #pragma unroll
        for (int r = 0; r < 4; ++r) {
            float mx = fmaxf(fmaxf(sacc[0][r], sacc[1][r]), fmaxf(sacc[2][r], sacc[3][r]));
            mx = fmaxf(mx, __shfl_xor(mx, 1));
            mx = fmaxf(mx, __shfl_xor(mx, 2));
            mx = fmaxf(mx, __shfl_xor(mx, 4));
            mx = fmaxf(mx, __shfl_xor(mx, 8));
            float p0 = __expf(sacc[0][r] - mx), p1 = __expf(sacc[1][r] - mx);
            float p2 = __expf(sacc[2][r] - mx), p3 = __expf(sacc[3][r] - mx);
            float s = p0 + p1 + p2 + p3;
            s += __shfl_xor(s, 1); s += __shfl_xor(s, 2);
            s += __shfl_xor(s, 4); s += __shfl_xor(s, 8);
            const float inv = 1.0f / s;
            float* arow = out + CTX + ((long)blockIdx.x * 64 + w * 16 + q * 4 + r) * 64;
            arow[ 0 + r16] = p0 * inv;
            arow[16 + r16] = p1 * inv;
            arow[32 + r16] = p2 * inv;
            arow[48 + r16] = p3 * inv;
        }
    }
}

// ---- kernel B: context = attn @ q (chunked LDS transpose of q) ----
__global__ __launch_bounds__(256, 4)
void ovo_ctx(const float* __restrict__ qm, const float* __restrict__ out_attn,
             float* __restrict__ out)
{
    __shared__ __align__(16) _Float16 qT[2][64 * QTP];   // q^T chunk [e][g]  36 KB

    const int t = threadIdx.x, lane = t & 63, w = t >> 6;   // 4 waves = 4 h-tiles
    const int r16 = lane & 15, q = lane >> 4;
    const long b = blockIdx.x;
    const long base = b * 64 * 512;
    const float4_t zf4 = {0.f, 0.f, 0.f, 0.f};

    // A-frags: attn rows h = w*16 + r16, k = kh*32 + q*8 + j (f32 -> f16)
    const float* ap = out_attn + (b * 64 + w * 16 + r16) * 64 + q * 8;
    half8_t pA0, pA1;
    {
        float4_t x = *(const float4_t*)(ap + 0),  y = *(const float4_t*)(ap + 4);
        pA0[0]=(_Float16)x[0]; pA0[1]=(_Float16)x[1]; pA0[2]=(_Float16)x[2]; pA0[3]=(_Float16)x[3];
        pA0[4]=(_Float16)y[0]; pA0[5]=(_Float16)y[1]; pA0[6]=(_Float16)y[2]; pA0[7]=(_Float16)y[3];
        float4_t z = *(const float4_t*)(ap + 32), u = *(const float4_t*)(ap + 36);
        pA1[0]=(_Float16)z[0]; pA1[1]=(_Float16)z[1]; pA1[2]=(_Float16)z[2]; pA1[3]=(_Float16)z[3];
        pA1[4]=(_Float16)u[0]; pA1[5]=(_Float16)u[1]; pA1[6]=(_Float16)u[2]; pA1[7]=(_Float16)u[3];
    }

    // staging map: g = t&63, e16 = (t>>6)*16
    const int sg = t & 63, se = (t >> 6) * 16;
    const float* qsrc = qm + base + (long)sg * 512 + se;
    float4_t rA[4], rB[4];

    #define QLOAD(R, c) do { \
        _Pragma("unroll") \
        for (int i = 0; i < 4; ++i) R[i] = *(const float4_t*)(qsrc + (c) * 64 + i * 4); \
    } while (0)
    #define QCOMMIT(R, buf) do { \
        _Pragma("unroll") \
        for (int i = 0; i < 4; ++i) \
            _Pragma("unroll") \
            for (int jj = 0; jj < 4; ++jj) \
                qT[buf][(se + i * 4 + jj) * QTP + sg] = (_Float16)R[i][jj]; \
    } while (0)

    #define BCOMP(c, buf) do { \
        _Pragma("unroll") \
        for (int et = 0; et < 4; ++et) { \
            half8_t b0 = *(const half8_t*)(&qT[buf][(et * 16 + r16) * QTP + q * 8]); \
            half8_t b1 = *(const half8_t*)(&qT[buf][(et * 16 + r16) * QTP + 32 + q * 8]); \
            float4_t acc = MFMA32(pA0, b0, zf4); \
            acc = MFMA32(pA1, b1, acc); \
            _Pragma("unroll") \
            for (int rr = 0; rr < 4; ++rr) \
                out[(b * 64 + w * 16 + q * 4 + rr) * 512 + (c) * 64 + et * 16 + r16] = acc[rr]; \
        } \
    } while (0)

    QLOAD(rA, 0);
    QCOMMIT(rA, 0);
    __syncthreads();
    #pragma unroll
    for (int cc = 0; cc < 8; cc += 2) {
        QLOAD(rB, cc + 1);
        BCOMP(cc, 0);
        QCOMMIT(rB, 1);
        __syncthreads();
        if (cc + 2 < 8) QLOAD(rA, cc + 2);
        BCOMP(cc + 1, 1);
        if (cc + 2 < 8) QCOMMIT(rA, 0);
        __syncthreads();
    }
}

extern "C" void kernel_launch(void* const* d_in, const int* in_sizes, int n_in,
                              void* d_out, int out_size, void* d_ws, size_t ws_size,
                              hipStream_t stream) {
    const float* o1 = (const float*)d_in[0];
    const float* o2 = (const float*)d_in[1];
    const float* o3 = (const float*)d_in[2];
    const float* qm = (const float*)d_in[3];
    const float* W  = (const float*)d_in[4];
    float* out = (float*)d_out;
    _Float16* W2 = (_Float16*)d_ws;           // 512 KB fragment-layout fp16 W

    w_pack<<<dim3(128), dim3(256), 0, stream>>>(W, W2);
    ovo_score<<<dim3(Bb), dim3(512), 0, stream>>>(o1, o2, o3, qm, W2, out);
    ovo_ctx<<<dim3(Bb), dim3(256), 0, stream>>>(qm, out + CTX, out);
}

// Round 8
// 198.714 us; speedup vs baseline: 1.0733x; 1.0733x over previous
//
#include <hip/hip_runtime.h>
#include <hip/hip_bf16.h>

typedef _Float16 half4_t __attribute__((ext_vector_type(4)));
typedef _Float16 half8_t __attribute__((ext_vector_type(8)));
typedef float    float4_t __attribute__((ext_vector_type(4)));

#define MFMA32(a, b, c) __builtin_amdgcn_mfma_f32_16x16x32_f16((a), (b), (c), 0, 0, 0)

constexpr int  Bb  = 1024;
constexpr long CTX = (long)Bb * 64 * 512;      // attn offset in d_out
constexpr int  SQP = 520;                      // sQ (q / V^T) row stride (halves)
constexpr int  SMP = 520;                      // sM row stride (halves)
constexpr int  SP  = 65;                       // sS row stride (f32)
constexpr int  QTP = 72;                       // qT row stride (halves), kernel B

// ---- pre-pass: pack W (f32 [e][f]) into fragment layout fp16 ----
__global__ void w_pack(const float* __restrict__ W, _Float16* __restrict__ W2) {
    const int t = blockIdx.x * 256 + threadIdx.x;      // 32768 threads
    const int lane = t & 63, grp = t >> 6;             // grp 0..511
    const int E = grp >> 4, c = grp & 15;
    const int r16 = lane & 15, q = lane >> 4;
    const float* src = W + (long)(E * 16 + r16) * 512 + c * 32 + q * 8;
    float4_t x = *(const float4_t*)(src);
    float4_t y = *(const float4_t*)(src + 4);
    half8_t h;
    h[0]=(_Float16)x[0]; h[1]=(_Float16)x[1]; h[2]=(_Float16)x[2]; h[3]=(_Float16)x[3];
    h[4]=(_Float16)y[0]; h[5]=(_Float16)y[1]; h[6]=(_Float16)y[2]; h[7]=(_Float16)y[3];
    *(half8_t*)(W2 + (long)t * 8) = h;
}

// ---- kernel A ----
__global__ __launch_bounds__(512, 2)
void ovo_score(const float* __restrict__ o1, const float* __restrict__ o2,
               const float* __restrict__ o3, const float* __restrict__ qm,
               const _Float16* __restrict__ W2, float* __restrict__ out)
{
    __shared__ __align__(16) _Float16 sQ[64 * SQP];      // q fp16, then V^T [g][e]; 66.6 KB
    __shared__ __align__(16) _Float16 sM[2][16 * SMP];   // mean h-chunk fp16 [h'][e]; 33.3 KB

    const int t = threadIdx.x, lane = t & 63, w = t >> 6;
    const int r16 = lane & 15, q = lane >> 4;
    const int gt = w & 3, eh = w >> 2;
    const long base = (long)blockIdx.x * 64 * 512;
    const float4_t zf4 = {0.f, 0.f, 0.f, 0.f};

    // ---- o-chunk staging: FLAT-LINEAR loads (wave instr = 1 KB contiguous) ----
    float4_t rA[12], rB[12];
    #define OLOAD(R, hc) do { \
        const long fb = base + (long)(hc) * 8192 + (long)t * 4; \
        _Pragma("unroll") for (int i = 0; i < 4; ++i) R[i]     = *(const float4_t*)(o1 + fb + i * 2048); \
        _Pragma("unroll") for (int i = 0; i < 4; ++i) R[4 + i] = *(const float4_t*)(o2 + fb + i * 2048); \
        _Pragma("unroll") for (int i = 0; i < 4; ++i) R[8 + i] = *(const float4_t*)(o3 + fb + i * 2048); \
    } while (0)
    #define OCOMMIT(R, buf) do { \
        _Pragma("unroll") for (int i = 0; i < 4; ++i) { \
            float4_t m = (R[i] + R[4 + i] + R[8 + i]) * (1.0f / 3.0f); \
            half4_t h; \
            h[0]=(_Float16)m[0]; h[1]=(_Float16)m[1]; h[2]=(_Float16)m[2]; h[3]=(_Float16)m[3]; \
            *(half4_t*)(&sM[buf][(i * 4 + (t >> 7)) * SMP + (t & 127) * 4]) = h; \
        } \
    } while (0)

    // ---- stage q fp16, flat-linear ----
    {
        const long qb = base + (long)t * 4;
        #pragma unroll
        for (int k = 0; k < 16; ++k) {
            float4_t v = *(const float4_t*)(qm + qb + (long)k * 2048);
            half4_t h;
            h[0]=(_Float16)v[0]; h[1]=(_Float16)v[1]; h[2]=(_Float16)v[2]; h[3]=(_Float16)v[3];
            *(half4_t*)(&sQ[(k * 4 + (t >> 7)) * SQP + (t & 127) * 4]) = h;
        }
    }
    OLOAD(rA, 0);                 // chunk 0 in flight across all of phase V
    __syncthreads();

    // ---- phase V: V^T[g][e] = sum_f q[g,f]*W[e,f]; wave w owns e-slice [64w,64w+64) ----
    float4_t vacc[4][4];   // [gt'][et]
    #pragma unroll
    for (int i = 0; i < 4; ++i)
        #pragma unroll
        for (int j = 0; j < 4; ++j) vacc[i][j] = zf4;

    #pragma unroll
    for (int c = 0; c < 16; ++c) {
        half8_t Aq[4], Bw[4];
        #pragma unroll
        for (int g2 = 0; g2 < 4; ++g2)
            Aq[g2] = *(const half8_t*)(&sQ[(g2 * 16 + r16) * SQP + c * 32 + q * 8]);
        #pragma unroll
        for (int et = 0; et < 4; ++et)
            Bw[et] = *(const half8_t*)(W2 + (long)((w * 4 + et) * 16 + c) * 512 + lane * 8);
        #pragma unroll
        for (int g2 = 0; g2 < 4; ++g2)
            #pragma unroll
            for (int et = 0; et < 4; ++et)
                vacc[g2][et] = MFMA32(Aq[g2], Bw[et], vacc[g2][et]);
    }
    __syncthreads();                       // q dead

    // V^T overwrites sQ; commit chunk 0; issue chunk 1
    #pragma unroll
    for (int g2 = 0; g2 < 4; ++g2)
        #pragma unroll
        for (int et = 0; et < 4; ++et)
            #pragma unroll
            for (int r = 0; r < 4; ++r)
                sQ[(g2 * 16 + q * 4 + r) * SQP + w * 64 + et * 16 + r16] =
                    (_Float16)vacc[g2][et][r];
    OCOMMIT(rA, 0);
    OLOAD(rB, 1);
    __syncthreads();

    // ---- phase S: 4 h-chunks; wave (gt, eh) computes [16h x 16g] over its e-half ----
    float4_t acc0 = zf4, acc1 = zf4, acc2 = zf4, acc3 = zf4;
    #define SCHUNK(ACC, buf) do { \
        _Pragma("unroll") for (int c = 0; c < 8; ++c) { \
            const int cc = eh * 8 + c; \
            half8_t af = *(const half8_t*)(&sM[buf][r16 * SMP + cc * 32 + q * 8]); \
            half8_t bf = *(const half8_t*)(&sQ[(gt * 16 + r16) * SQP + cc * 32 + q * 8]); \
            ACC = MFMA32(af, bf, ACC); \
        } \
    } while (0)

    SCHUNK(acc0, 0); OCOMMIT(rB, 1); OLOAD(rA, 2);
    __syncthreads();
    SCHUNK(acc1, 1); OCOMMIT(rA, 0); OLOAD(rB, 3);
    __syncthreads();
    SCHUNK(acc2, 0); OCOMMIT(rB, 1);
    __syncthreads();
    SCHUNK(acc3, 1);
    __syncthreads();

    // ---- reduce e-halves (LDS overlay on sM) + full score to sS (overlay on sQ) ----
    float4_t* part4 = reinterpret_cast<float4_t*>(&sM[0][0]);
    float*    sS    = reinterpret_cast<float*>(&sQ[0]);
    if (eh == 1) {
        part4[(gt * 4 + 0) * 64 + lane] = acc0;
        part4[(gt * 4 + 1) * 64 + lane] = acc1;
        part4[(gt * 4 + 2) * 64 + lane] = acc2;
        part4[(gt * 4 + 3) * 64 + lane] = acc3;
    }
    __syncthreads();
    if (eh == 0) {
        acc0 += part4[(gt * 4 + 0) * 64 + lane];
        acc1 += part4[(gt * 4 + 1) * 64 + lane];
        acc2 += part4[(gt * 4 + 2) * 64 + lane];
        acc3 += part4[(gt * 4 + 3) * 64 + lane];
        #pragma unroll
        for (int r = 0; r < 4; ++r) {
            sS[( 0 + q * 4 + r) * SP + gt * 16 + r16] = acc0[r];
            sS[(16 + q * 4 + r) * SP + gt * 16 + r16] = acc1[r];
            sS[(32 + q * 4 + r) * SP + gt * 16 + r16] = acc2[r];
            sS[(48 + q * 4 + r) * SP + gt * 16 + r16] = acc3[r];
        }
    }
    __syncthreads();

    // ---- softmax over g (waves 0-3: 16 rows each, 4 lanes/row) ----
    if (w < 4) {
        const int r  = w * 16 + r16;
        const int qd = lane >> 4;
        const float* srow = sS + r * SP + qd * 16;
        float v[16];
        float mx = -1e30f;
        #pragma unroll
        for (int i = 0; i < 16; ++i) { v[i] = srow[i]; mx = fmaxf(mx, v[i]); }
        mx = fmaxf(mx, __shfl_xor(mx, 16));
        mx = fmaxf(mx, __shfl_xor(mx, 32));
        float sum = 0.f;
        #pragma unroll
        for (int i = 0; i < 16; ++i) { v[i] = __expf(v[i] - mx); sum += v[i]; }
        sum += __shfl_xor(sum, 16);
        sum += __shfl_xor(sum, 32);
        const float inv = 1.0f / sum;
        float* aout = out + CTX + ((long)blockIdx.x * 64 + r) * 64 + qd * 16;
        #pragma unroll
        for (int i = 0; i < 16; ++i) aout[i] = v[i] * inv;
    }
}

// ---- kernel B: context = attn @ q (unchanged; qm reads are L3-hot) ----
__global__ __launch_bounds__(256, 4)
void ovo_ctx(const float* __restrict__ qm, const float* __restrict__ out_attn,
             float* __restrict__ out)
{
    __shared__ __align__(16) _Float16 qT[2][64 * QTP];   // q^T chunk [e][g]  36 KB

    const int t = threadIdx.x, lane = t & 63, w = t >> 6;
    const int r16 = lane & 15, q = lane >> 4;
    const long b = blockIdx.x;
    const long base = b * 64 * 512;
    const float4_t zf4 = {0.f, 0.f, 0.f, 0.f};

    const float* ap = out_attn + (b * 64 + w * 16 + r16) * 64 + q * 8;
    half8_t pA0, pA1;
    {
        float4_t x = *(const float4_t*)(ap + 0),  y = *(const float4_t*)(ap + 4);
        pA0[0]=(_Float16)x[0]; pA0[1]=(_Float16)x[1]; pA0[2]=(_Float16)x[2]; pA0[3]=(_Float16)x[3];
        pA0[4]=(_Float16)y[0]; pA0[5]=(_Float16)y[1]; pA0[6]=(_Float16)y[2]; pA0[7]=(_Float16)y[3];
        float4_t z = *(const float4_t*)(ap + 32), u = *(const float4_t*)(ap + 36);
        pA1[0]=(_Float16)z[0]; pA1[1]=(_Float16)z[1]; pA1[2]=(_Float16)z[2]; pA1[3]=(_Float16)z[3];
        pA1[4]=(_Float16)u[0]; pA1[5]=(_Float16)u[1]; pA1[6]=(_Float16)u[2]; pA1[7]=(_Float16)u[3];
    }

    const int sg = t & 63, se = (t >> 6) * 16;
    const float* qsrc = qm + base + (long)sg * 512 + se;
    float4_t rA[4], rB[4];

    #define QLOAD(R, c) do { \
        _Pragma("unroll") \
        for (int i = 0; i < 4; ++i) R[i] = *(const float4_t*)(qsrc + (c) * 64 + i * 4); \
    } while (0)
    #define QCOMMIT(R, buf) do { \
        _Pragma("unroll") \
        for (int i = 0; i < 4; ++i) \
            _Pragma("unroll") \
            for (int jj = 0; jj < 4; ++jj) \
                qT[buf][(se + i * 4 + jj) * QTP + sg] = (_Float16)R[i][jj]; \
    } while (0)
    #define BCOMP(c, buf) do { \
        _Pragma("unroll") \
        for (int et = 0; et < 4; ++et) { \
            half8_t b0 = *(const half8_t*)(&qT[buf][(et * 16 + r16) * QTP + q * 8]); \
            half8_t b1 = *(const half8_t*)(&qT[buf][(et * 16 + r16) * QTP + 32 + q * 8]); \
            float4_t acc = MFMA32(pA0, b0, zf4); \
            acc = MFMA32(pA1, b1, acc); \
            _Pragma("unroll") \
            for (int rr = 0; rr < 4; ++rr) \
                out[(b * 64 + w * 16 + q * 4 + rr) * 512 + (c) * 64 + et * 16 + r16] = acc[rr]; \
        } \
    } while (0)

    QLOAD(rA, 0);
    QCOMMIT(rA, 0);
    __syncthreads();
    #pragma unroll
    for (int cc = 0; cc < 8; cc += 2) {
        QLOAD(rB, cc + 1);
        BCOMP(cc, 0);
        QCOMMIT(rB, 1);
        __syncthreads();
        if (cc + 2 < 8) QLOAD(rA, cc + 2);
        BCOMP(cc + 1, 1);
        if (cc + 2 < 8) QCOMMIT(rA, 0);
        __syncthreads();
    }
}

extern "C" void kernel_launch(void* const* d_in, const int* in_sizes, int n_in,
                              void* d_out, int out_size, void* d_ws, size_t ws_size,
                              hipStream_t stream) {
    const float* o1 = (const float*)d_in[0];
    const float* o2 = (const float*)d_in[1];
    const float* o3 = (const float*)d_in[2];
    const float* qm = (const float*)d_in[3];
    const float* W  = (const float*)d_in[4];
    float* out = (float*)d_out;
    _Float16* W2 = (_Float16*)d_ws;           // 512 KB fragment-layout fp16 W

    w_pack<<<dim3(128), dim3(256), 0, stream>>>(W, W2);
    ovo_score<<<dim3(Bb), dim3(512), 0, stream>>>(o1, o2, o3, qm, W2, out);
    ovo_ctx<<<dim3(Bb), dim3(256), 0, stream>>>(qm, out + CTX, out);
}